// Round 1
// baseline (197.546 us; speedup 1.0000x reference)
//
#include <hip/hip_runtime.h>
#include <hip/hip_cooperative_groups.h>

namespace cg = cooperative_groups;

#define B 8
#define H 512
#define W 512
#define HW (H * W)      // 262144 = 2^18
#define BHW (B * H * W) // 2097152

// d_ws layout:
//   [0   ..127]  double sums[16]   (gt: b0..7, seg: b8..15)
//   [128 ..191]  uint   maxbuf[16]
//   [192 ..195]  uint   counter
//   [256 ..]     u16 ud_gt[BHW], u16 ud_seg[BHW]   (4 MiB each)

// ---------------------------------------------------------------------------
// Fused kernel: phase 1 = vertical 1D distance (one column-strip per block),
// grid-wide cooperative barrier, phase 2 = per-row parabola min + fused loss.
// 256 blocks x 512 threads = 1 block/CU, co-resident (cooperative launch).
// XCD-aware mapping: batch b's strips AND rows live on blocks with bx%8==b,
// so the u16 intermediates + inputs stay in that XCD's L2 across the barrier.
// (Perf heuristic only -- correctness comes from grid.sync's device fences.)
// ---------------------------------------------------------------------------
__global__ __launch_bounds__(512) void fused_kernel(
    const float* __restrict__ output, const int* __restrict__ target,
    unsigned short* __restrict__ ud_gt, unsigned short* __restrict__ ud_seg,
    unsigned int* __restrict__ hdr, double* __restrict__ sums,
    unsigned int* __restrict__ maxbuf, unsigned int* __restrict__ counter,
    float* __restrict__ out) {
  const int tid = threadIdx.x;
  const int bx = blockIdx.x;

  __shared__ union {
    struct { int last[16][32]; int first[16][32]; } v;  // 4 KiB (phase 1)
    struct { float g[8][W]; float s[8][W]; } h2;        // 32 KiB (phase 2)
  } sm;

  // Zero the 256B header with ATOMIC stores so it is ordered at the same
  // coherence point as the phase-2 device-scope atomics (no kernel-end flush
  // between phases anymore).
  if (bx == 0 && tid < 64) atomicExch(&hdr[tid], 0u);

  // ---- phase 1: vertical 1D distance, one (strip, batch, mask) per block --
  {
    const int g = bx & 15;        // group = b + 8*maskSel  (bx%8 == b)
    const int strip = bx >> 4;    // 0..15
    const int b = g & 7;
    const int maskSel = g >> 3;
    const int c = tid & 31;       // col within strip
    const int col = strip * 32 + c;
    const int seg = tid >> 5;     // 0..15
    const int h0 = seg * 32;

    const int* tsrc = target + (size_t)b * HW + col;
    const float* osrc = output + (size_t)(2 * b + 1) * HW + col;
    unsigned short* dst = (maskSel ? ud_seg : ud_gt) + (size_t)b * HW + col;

    // bit i set <=> pixel at row h0+i is background (False)
    unsigned int bits = 0;
    if (maskSel == 0) {
#pragma unroll
      for (int i = 0; i < 32; ++i) {
        if (!(tsrc[(h0 + i) * W] > 0)) bits |= 1u << i;
      }
    } else {
#pragma unroll
      for (int i = 0; i < 32; ++i) {
        if (!(osrc[(h0 + i) * W] > 0.5f)) bits |= 1u << i;
      }
    }

    sm.v.last[seg][c] = bits ? (h0 + 31 - __clz(bits)) : -1000001;
    sm.v.first[seg][c] = bits ? (h0 + __ffs(bits) - 1) : 2000000;
    __syncthreads();

    int inLF = -1000001; // no False above: h - inLF > 65535 -> clamps
    int inNF = 2000000;  // no False below: nf - h > 65535 -> clamps
#pragma unroll
    for (int s = 0; s < 16; ++s) {
      int sl = sm.v.last[s][c];
      int sf = sm.v.first[s][c];
      if (s < seg) inLF = max(inLF, sl);
      if (s > seg) inNF = min(inNF, sf);
    }

#pragma unroll
    for (int i = 0; i < 32; ++i) {
      const int h = h0 + i;
      unsigned int below = bits & (0xFFFFFFFFu >> (31 - i));
      unsigned int above = bits >> i;
      int lf = below ? (h0 + 31 - __clz(below)) : inLF;
      int nf = above ? (h + __ffs(above) - 1) : inNF;
      int v = min(min(h - lf, nf - h), 65535);
      dst[h * W] = (unsigned short)v;
    }
  }

  // ---- grid-wide barrier: release u16 stores, then acquire for phase 2 ----
  __threadfence();
  cg::this_grid().sync();
  __threadfence();

  // ---- phase 2: parabola min + fused loss; 2 rows per wave ----------------
  const int lane = tid & 63;
  const int wave = tid >> 6;   // 0..7
  const int bb = bx & 7;       // batch: same XCD whose L2 holds its strips
  const int blk = bx >> 3;     // 0..31 -> 16 rows each

  float* sgw = sm.h2.g[wave];
  float* ssw = sm.h2.s[wave];

  auto sq2 = [](unsigned int u, float& a, float& bq) {
    float x = (float)(u & 0xffffu);
    float y = (float)(u >> 16);
    a = x * x;
    bq = y * y;
  };

  double sgd = 0.0, ssd = 0.0;
  float mgAll = 0.f, msAll = 0.f;

  for (int half = 0; half < 2; ++half) {
    const int rb = bb * H + blk * 16 + half * 8 + wave; // global row 0..4095
    const int h = rb & (H - 1);

    // one uint4 per lane = 8 u16 covers the whole 512-wide row per wave
    const unsigned short* gRow = ud_gt + (size_t)rb * W;
    const unsigned short* sRow = ud_seg + (size_t)rb * W;
    uint4 gu = ((const uint4*)gRow)[lane];
    uint4 su = ((const uint4*)sRow)[lane];

    float4 lo, hi;
    sq2(gu.x, lo.x, lo.y); sq2(gu.y, lo.z, lo.w);
    sq2(gu.z, hi.x, hi.y); sq2(gu.w, hi.z, hi.w);
    ((float4*)sgw)[2 * lane] = lo;
    ((float4*)sgw)[2 * lane + 1] = hi;
    sq2(su.x, lo.x, lo.y); sq2(su.y, lo.z, lo.w);
    sq2(su.z, hi.x, hi.y); sq2(su.w, hi.z, hi.w);
    ((float4*)ssw)[2 * lane] = lo;
    ((float4*)ssw)[2 * lane + 1] = hi;
    // wave-private LDS slice: no __syncthreads needed (lgkmcnt ordering only)

    float bg[8], bs[8];
    float m = 0.f;
#pragma unroll
    for (int i = 0; i < 8; ++i) {
      int j = lane + 64 * i;
      bg[i] = sgw[j];
      bs[i] = ssw[j];
      m = fmaxf(m, fmaxf(bg[i], bs[i]));
    }
    for (int r = 1; r < W; ++r) {
      float rr = (float)(r * r);
      if (rr >= m) break;  // exact early exit: s[k]+rr >= rr >= best
      m = 0.f;
#pragma unroll
      for (int i = 0; i < 8; ++i) {
        int j = lane + 64 * i;
        int kl = j - r, kr = j + r;
        float gl = (kl >= 0) ? sgw[kl] : 4e12f;
        float gr = (kr < W) ? sgw[kr] : 4e12f;
        float sl = (kl >= 0) ? ssw[kl] : 4e12f;
        float sr = (kr < W) ? ssw[kr] : 4e12f;
        bg[i] = fminf(bg[i], fminf(gl + rr, gr + rr));
        bs[i] = fminf(bs[i], fminf(sl + rr, sr + rr));
        m = fmaxf(m, fmaxf(bg[i], bs[i]));
      }
    }

    // fused loss: dsq=(out1-gt)^2; accumulate dsq*dt2 per mask and max(dt2)
    const float* oRow = output + (size_t)(2 * bb + 1) * HW + (size_t)h * W;
    const int* tRow = target + (size_t)bb * HW + (size_t)h * W;
    float sgf = 0.f, ssf = 0.f, mg = 0.f, ms = 0.f;
#pragma unroll
    for (int i = 0; i < 8; ++i) {
      int j = lane + 64 * i;
      float o = oRow[j];
      float t = (float)tRow[j];
      float dq = (o - t) * (o - t);
      sgf += dq * bg[i];
      ssf += dq * bs[i];
      mg = fmaxf(mg, bg[i]);
      ms = fmaxf(ms, bs[i]);
    }
    sgd += (double)sgf;
    ssd += (double)ssf;
    mgAll = fmaxf(mgAll, mg);
    msAll = fmaxf(msAll, ms);
  }

  // wave reduction
#pragma unroll
  for (int off = 32; off; off >>= 1) {
    sgd += __shfl_down(sgd, off);
    ssd += __shfl_down(ssd, off);
    mgAll = fmaxf(mgAll, __shfl_down(mgAll, off));
    msAll = fmaxf(msAll, __shfl_down(msAll, off));
  }
  __shared__ double bsg[8], bss[8];
  __shared__ float bmg[8], bms[8];
  __shared__ unsigned int lastFlag;
  if (lane == 0) {
    bsg[wave] = sgd;
    bss[wave] = ssd;
    bmg[wave] = mgAll;
    bms[wave] = msAll;
  }
  __syncthreads();
  if (tid == 0) {
    double tg = 0.0, ts = 0.0;
    float xg = 0.f, xs = 0.f;
#pragma unroll
    for (int wv = 0; wv < 8; ++wv) {
      tg += bsg[wv];
      ts += bss[wv];
      xg = fmaxf(xg, bmg[wv]);
      xs = fmaxf(xs, bms[wv]);
    }
    atomicAdd(&sums[bb], tg);
    atomicAdd(&sums[8 + bb], ts);
    atomicMax(&maxbuf[bb], __float_as_uint(xg)); // vals >= 0: uint order ok
    atomicMax(&maxbuf[8 + bb], __float_as_uint(xs));
    __threadfence(); // release our partials before announcing
    unsigned int old = atomicAdd(counter, 1u);
    lastFlag = (old == 255u) ? 1u : 0u; // 256 blocks arrive
  }
  __syncthreads();

  if (lastFlag && tid < 64) {
    __threadfence(); // acquire
    double t = 0.0;
    if (tid < 8) {
      // non-destructive atomic RMW read-back: coherent across XCDs
      double sgv = atomicAdd(&sums[tid], 0.0);
      double ssv = atomicAdd(&sums[8 + tid], 0.0);
      float xg = __uint_as_float(atomicMax(&maxbuf[tid], 0u));
      float xs = __uint_as_float(atomicMax(&maxbuf[8 + tid], 0u));
      t = sgv / (double)(xg > 0.f ? xg : 1.f) +
          ssv / (double)(xs > 0.f ? xs : 1.f);
    }
    t += __shfl_down(t, 4);
    t += __shfl_down(t, 2);
    t += __shfl_down(t, 1);
    if (tid == 0) out[0] = (float)(t * (1.0 / (double)BHW));
  }
}

// ---------------------------------------------------------------------------
// Fallback path (previous verified two-kernel version) in case the
// cooperative launch is rejected by the runtime / graph capture.
// ---------------------------------------------------------------------------
__global__ __launch_bounds__(512) void vert_kernel(
    const float* __restrict__ output, const int* __restrict__ target,
    unsigned short* __restrict__ ud_gt, unsigned short* __restrict__ ud_seg,
    unsigned int* __restrict__ hdr) {
  const int tid = threadIdx.x;
  const int bx = blockIdx.x;
  if (bx == 0 && tid < 64) hdr[tid] = 0u;

  const int strip = bx & 15;
  const int b = (bx >> 4) & 7;
  const int maskSel = bx >> 7;
  const int c = tid & 31;
  const int col = strip * 32 + c;
  const int seg = tid >> 5;
  const int h0 = seg * 32;

  const int* tsrc = target + (size_t)b * HW + col;
  const float* osrc = output + (size_t)(2 * b + 1) * HW + col;
  unsigned short* dst = (maskSel ? ud_seg : ud_gt) + (size_t)b * HW + col;

  unsigned int bits = 0;
  if (maskSel == 0) {
#pragma unroll
    for (int i = 0; i < 32; ++i) {
      if (!(tsrc[(h0 + i) * W] > 0)) bits |= 1u << i;
    }
  } else {
#pragma unroll
    for (int i = 0; i < 32; ++i) {
      if (!(osrc[(h0 + i) * W] > 0.5f)) bits |= 1u << i;
    }
  }

  __shared__ int sLast[16][32];
  __shared__ int sFirst[16][32];
  sLast[seg][c] = bits ? (h0 + 31 - __clz(bits)) : -1000001;
  sFirst[seg][c] = bits ? (h0 + __ffs(bits) - 1) : 2000000;
  __syncthreads();

  int inLF = -1000001;
  int inNF = 2000000;
#pragma unroll
  for (int s = 0; s < 16; ++s) {
    int sl = sLast[s][c];
    int sf = sFirst[s][c];
    if (s < seg) inLF = max(inLF, sl);
    if (s > seg) inNF = min(inNF, sf);
  }

#pragma unroll
  for (int i = 0; i < 32; ++i) {
    const int h = h0 + i;
    unsigned int below = bits & (0xFFFFFFFFu >> (31 - i));
    unsigned int above = bits >> i;
    int lf = below ? (h0 + 31 - __clz(below)) : inLF;
    int nf = above ? (h + __ffs(above) - 1) : inNF;
    int v = min(min(h - lf, nf - h), 65535);
    dst[h * W] = (unsigned short)v;
  }
}

__global__ __launch_bounds__(512) void horiz_kernel(
    const float* __restrict__ output, const int* __restrict__ target,
    const unsigned short* __restrict__ ud_gt,
    const unsigned short* __restrict__ ud_seg, double* __restrict__ sums,
    unsigned int* __restrict__ maxbuf, unsigned int* __restrict__ counter,
    float* __restrict__ out) {
  const int tid = threadIdx.x;
  const int lane = tid & 63;
  const int wave = tid >> 6;
  const int rb = blockIdx.x * 8 + wave;
  const int b = rb >> 9;
  const int h = rb & (H - 1);

  __shared__ float sg[8][W];
  __shared__ float ss[8][W];

  const unsigned short* gRow = ud_gt + (size_t)rb * W;
  const unsigned short* sRow = ud_seg + (size_t)rb * W;
  uint4 gu = ((const uint4*)gRow)[lane];
  uint4 su = ((const uint4*)sRow)[lane];

  auto sq2 = [](unsigned int u, float& a, float& bq) {
    float x = (float)(u & 0xffffu);
    float y = (float)(u >> 16);
    a = x * x;
    bq = y * y;
  };
  float4 lo, hi;
  sq2(gu.x, lo.x, lo.y); sq2(gu.y, lo.z, lo.w);
  sq2(gu.z, hi.x, hi.y); sq2(gu.w, hi.z, hi.w);
  ((float4*)sg[wave])[2 * lane] = lo;
  ((float4*)sg[wave])[2 * lane + 1] = hi;
  sq2(su.x, lo.x, lo.y); sq2(su.y, lo.z, lo.w);
  sq2(su.z, hi.x, hi.y); sq2(su.w, hi.z, hi.w);
  ((float4*)ss[wave])[2 * lane] = lo;
  ((float4*)ss[wave])[2 * lane + 1] = hi;
  __syncthreads();

  const float* g = sg[wave];
  const float* s = ss[wave];
  float bg[8], bs[8];
  float m = 0.f;
#pragma unroll
  for (int i = 0; i < 8; ++i) {
    int j = lane + 64 * i;
    bg[i] = g[j];
    bs[i] = s[j];
    m = fmaxf(m, fmaxf(bg[i], bs[i]));
  }
  for (int r = 1; r < W; ++r) {
    float rr = (float)(r * r);
    if (rr >= m) break;
    m = 0.f;
#pragma unroll
    for (int i = 0; i < 8; ++i) {
      int j = lane + 64 * i;
      int kl = j - r, kr = j + r;
      float gl = (kl >= 0) ? g[kl] : 4e12f;
      float gr = (kr < W) ? g[kr] : 4e12f;
      float sl = (kl >= 0) ? s[kl] : 4e12f;
      float sr = (kr < W) ? s[kr] : 4e12f;
      bg[i] = fminf(bg[i], fminf(gl + rr, gr + rr));
      bs[i] = fminf(bs[i], fminf(sl + rr, sr + rr));
      m = fmaxf(m, fmaxf(bg[i], bs[i]));
    }
  }

  const float* oRow = output + (size_t)(2 * b + 1) * HW + (size_t)h * W;
  const int* tRow = target + (size_t)b * HW + (size_t)h * W;
  float mg = 0.f, ms = 0.f, sgf = 0.f, ssf = 0.f;
#pragma unroll
  for (int i = 0; i < 8; ++i) {
    int j = lane + 64 * i;
    float o = oRow[j];
    float t = (float)tRow[j];
    float dq = (o - t) * (o - t);
    sgf += dq * bg[i];
    ssf += dq * bs[i];
    mg = fmaxf(mg, bg[i]);
    ms = fmaxf(ms, bs[i]);
  }
  double sgd = (double)sgf, ssd = (double)ssf;
#pragma unroll
  for (int off = 32; off; off >>= 1) {
    sgd += __shfl_down(sgd, off);
    ssd += __shfl_down(ssd, off);
    mg = fmaxf(mg, __shfl_down(mg, off));
    ms = fmaxf(ms, __shfl_down(ms, off));
  }
  __shared__ double bsg[8], bss[8];
  __shared__ float bmg[8], bms[8];
  __shared__ unsigned int lastFlag;
  if (lane == 0) {
    bsg[wave] = sgd;
    bss[wave] = ssd;
    bmg[wave] = mg;
    bms[wave] = ms;
  }
  __syncthreads();
  if (tid == 0) {
    double tg = 0.0, ts = 0.0;
    float xg = 0.f, xs = 0.f;
#pragma unroll
    for (int wv = 0; wv < 8; ++wv) {
      tg += bsg[wv];
      ts += bss[wv];
      xg = fmaxf(xg, bmg[wv]);
      xs = fmaxf(xs, bms[wv]);
    }
    atomicAdd(&sums[b], tg);
    atomicAdd(&sums[8 + b], ts);
    atomicMax(&maxbuf[b], __float_as_uint(xg));
    atomicMax(&maxbuf[8 + b], __float_as_uint(xs));
    __threadfence();
    unsigned int old = atomicAdd(counter, 1u);
    lastFlag = (old == (unsigned int)(B * H / 8 - 1)) ? 1u : 0u;
  }
  __syncthreads();

  if (lastFlag && tid < 64) {
    __threadfence();
    double t = 0.0;
    if (tid < 8) {
      double sgv = atomicAdd(&sums[tid], 0.0);
      double ssv = atomicAdd(&sums[8 + tid], 0.0);
      float xg = __uint_as_float(atomicMax(&maxbuf[tid], 0u));
      float xs = __uint_as_float(atomicMax(&maxbuf[8 + tid], 0u));
      t = sgv / (double)(xg > 0.f ? xg : 1.f) +
          ssv / (double)(xs > 0.f ? xs : 1.f);
    }
    t += __shfl_down(t, 4);
    t += __shfl_down(t, 2);
    t += __shfl_down(t, 1);
    if (tid == 0) out[0] = (float)(t * (1.0 / (double)BHW));
  }
}

extern "C" void kernel_launch(void* const* d_in, const int* in_sizes, int n_in,
                              void* d_out, int out_size, void* d_ws,
                              size_t ws_size, hipStream_t stream) {
  const float* output = (const float*)d_in[0]; // [8,2,512,512] f32
  const int* target = (const int*)d_in[1];     // [8,1,512,512] i32

  double* sums = (double*)d_ws;
  unsigned int* maxbuf = (unsigned int*)((char*)d_ws + 128);
  unsigned int* counter = (unsigned int*)((char*)d_ws + 192);
  unsigned int* hdr = (unsigned int*)d_ws;
  unsigned short* ud_gt = (unsigned short*)((char*)d_ws + 256);
  unsigned short* ud_seg = ud_gt + BHW;
  float* outp = (float*)d_out;

  void* args[] = {&output, &target, &ud_gt, &ud_seg, &hdr,
                  &sums,   &maxbuf, &counter, &outp};
  hipError_t err = hipLaunchCooperativeKernel(
      reinterpret_cast<void*>(fused_kernel), dim3(256), dim3(512), args, 0,
      stream);
  if (err != hipSuccess) {
    // fallback: previous verified two-kernel path
    vert_kernel<<<dim3(256), 512, 0, stream>>>(output, target, ud_gt, ud_seg,
                                               hdr);
    horiz_kernel<<<dim3(B * H / 8), 512, 0, stream>>>(
        output, target, ud_gt, ud_seg, sums, maxbuf, counter, outp);
  }
}

// Round 2
// 93.079 us; speedup vs baseline: 2.1223x; 2.1223x over previous
//
#include <hip/hip_runtime.h>

#define B 8
#define H 512
#define W 512
#define HW (H * W)      // 262144 = 2^18
#define BHW (B * H * W) // 2097152

// d_ws layout:
//   [0   ..127]  double sums[16]   (gt: b0..7, seg: b8..15)
//   [128 ..191]  uint   maxbuf[16]
//   [192 ..195]  uint   counter
//   [256 ..]     u16 ud_gt[BHW], u16 ud_seg[BHW]   (4 MiB each)

// ---------------------------------------------------------------------------
// Kernel V: vertical 1D distance along H, both masks, u16 output.
// fw[h] = h - lastFalse(<=h), bw[h] = nextFalse(>=h) - h; min, clamp 65535.
// Thread = (column, 32-row segment); mask packed in a u32; per-row distances
// via clz/ffs; cross-segment fixup via LDS summary + 1 barrier.
// XCD-affinity: batch b on blocks with bx%8==b (default round-robin block->XCD
// mapping on MI355X) so batch b's inputs + u16 tiles land in XCD b's L2 and
// are re-read from L2 by the horiz kernel (same mapping). Perf heuristic only:
// correctness does not depend on the mapping (kernel-boundary coherence).
// ---------------------------------------------------------------------------
__global__ __launch_bounds__(512) void vert_kernel(
    const float* __restrict__ output, const int* __restrict__ target,
    unsigned short* __restrict__ ud_gt, unsigned short* __restrict__ ud_seg,
    unsigned int* __restrict__ hdr) {
  const int tid = threadIdx.x;
  const int bx = blockIdx.x;
  if (bx == 0 && tid < 64) hdr[tid] = 0u; // zero 256B header

  const int b = bx & 7;             // batch -> XCD b
  const int strip = (bx >> 3) & 15; // 16 strips of 32 cols
  const int maskSel = bx >> 7;      // 0: gt, 1: seg
  const int c = tid & 31;           // col within strip
  const int col = strip * 32 + c;   // 0..511
  const int seg = tid >> 5;         // 0..15
  const int h0 = seg * 32;

  const int* tsrc = target + (size_t)b * HW + col;
  const float* osrc = output + (size_t)(2 * b + 1) * HW + col;
  unsigned short* dst = (maskSel ? ud_seg : ud_gt) + (size_t)b * HW + col;

  // bit i set <=> pixel at row h0+i is background (False)
  unsigned int bits = 0;
  if (maskSel == 0) {
#pragma unroll
    for (int i = 0; i < 32; ++i) {
      if (!(tsrc[(h0 + i) * W] > 0)) bits |= 1u << i;
    }
  } else {
#pragma unroll
    for (int i = 0; i < 32; ++i) {
      if (!(osrc[(h0 + i) * W] > 0.5f)) bits |= 1u << i;
    }
  }

  __shared__ int sLast[16][32];
  __shared__ int sFirst[16][32];
  sLast[seg][c] = bits ? (h0 + 31 - __clz(bits)) : -1000001;
  sFirst[seg][c] = bits ? (h0 + __ffs(bits) - 1) : 2000000;
  __syncthreads();

  int inLF = -1000001; // no False above: h - inLF > 65535 -> clamps
  int inNF = 2000000;  // no False below: nf - h > 65535 -> clamps
#pragma unroll
  for (int s = 0; s < 16; ++s) {
    int sl = sLast[s][c];
    int sf = sFirst[s][c];
    if (s < seg) inLF = max(inLF, sl);
    if (s > seg) inNF = min(inNF, sf);
  }

#pragma unroll
  for (int i = 0; i < 32; ++i) {
    const int h = h0 + i;
    unsigned int below = bits & (0xFFFFFFFFu >> (31 - i));
    unsigned int above = bits >> i;
    int lf = below ? (h0 + 31 - __clz(below)) : inLF;
    int nf = above ? (h + __ffs(above) - 1) : inNF;
    int v = min(min(h - lf, nf - h), 65535);
    dst[h * W] = (unsigned short)v;
  }
}

// ---------------------------------------------------------------------------
// Kernel H: per-row parabola min (exact early-exit) for both masks + fused
// loss accumulation + last-block finalize. One wave per row, 8 cols/lane.
// Early exit is bitwise-exact: skipped candidates s[k]+rr >= rr >= best.
// XCD-affinity: batch b rows on blocks with bx%8==b (matches vert_kernel, so
// u16 + input reads hit XCD b's L2). Loss-input loads are issued BEFORE the
// parabola loop (latency hides under ~2000 cy of compute). No barrier after
// LDS staging: each wave touches only its own LDS slice.
// ---------------------------------------------------------------------------
__global__ __launch_bounds__(512) void horiz_kernel(
    const float* __restrict__ output, const int* __restrict__ target,
    const unsigned short* __restrict__ ud_gt,
    const unsigned short* __restrict__ ud_seg, double* __restrict__ sums,
    unsigned int* __restrict__ maxbuf, unsigned int* __restrict__ counter,
    float* __restrict__ out) {
  const int tid = threadIdx.x;
  const int lane = tid & 63;
  const int wave = tid >> 6;          // 0..7
  const int b = blockIdx.x & 7;       // batch -> XCD b
  const int rg = blockIdx.x >> 3;     // 0..63: row-group within batch
  const int rb = b * H + rg * 8 + wave; // global row index 0..4095
  const int h = rb & (H - 1);

  __shared__ float sg[8][W];
  __shared__ float ss[8][W];

  // one uint4 per lane = 8 u16 covers the whole 512-wide row per wave
  const unsigned short* gRow = ud_gt + (size_t)rb * W;
  const unsigned short* sRow = ud_seg + (size_t)rb * W;
  uint4 gu = ((const uint4*)gRow)[lane];
  uint4 su = ((const uint4*)sRow)[lane];

  // issue loss-input loads EARLY; consumed after the parabola loop
  const float* oRow = output + (size_t)(2 * b + 1) * HW + (size_t)h * W;
  const int* tRow = target + (size_t)b * HW + (size_t)h * W;
  float oV[8];
  float tV[8];
#pragma unroll
  for (int i = 0; i < 8; ++i) {
    int j = lane + 64 * i;
    oV[i] = oRow[j];
    tV[i] = (float)tRow[j];
  }

  auto sq2 = [](unsigned int u, float& a, float& bq) {
    float x = (float)(u & 0xffffu);
    float y = (float)(u >> 16);
    a = x * x;
    bq = y * y;
  };
  float4 lo, hi;
  sq2(gu.x, lo.x, lo.y); sq2(gu.y, lo.z, lo.w);
  sq2(gu.z, hi.x, hi.y); sq2(gu.w, hi.z, hi.w);
  ((float4*)sg[wave])[2 * lane] = lo;
  ((float4*)sg[wave])[2 * lane + 1] = hi;
  sq2(su.x, lo.x, lo.y); sq2(su.y, lo.z, lo.w);
  sq2(su.z, hi.x, hi.y); sq2(su.w, hi.z, hi.w);
  ((float4*)ss[wave])[2 * lane] = lo;
  ((float4*)ss[wave])[2 * lane + 1] = hi;
  // wave-private LDS slice: no __syncthreads needed (lgkmcnt ordering only)

  const float* g = sg[wave];
  const float* s = ss[wave];
  float bg[8], bs[8];
  float m = 0.f;
#pragma unroll
  for (int i = 0; i < 8; ++i) {
    int j = lane + 64 * i;
    bg[i] = g[j];
    bs[i] = s[j];
    m = fmaxf(m, fmaxf(bg[i], bs[i]));
  }
  for (int r = 1; r < W; ++r) {
    float rr = (float)(r * r);
    if (rr >= m) break; // exact: skipped candidates s[k]+rr >= rr >= best
    m = 0.f;
#pragma unroll
    for (int i = 0; i < 8; ++i) {
      int j = lane + 64 * i;
      int kl = j - r, kr = j + r;
      float gl = (kl >= 0) ? g[kl] : 4e12f;
      float gr = (kr < W) ? g[kr] : 4e12f;
      float sl = (kl >= 0) ? s[kl] : 4e12f;
      float sr = (kr < W) ? s[kr] : 4e12f;
      bg[i] = fminf(bg[i], fminf(gl + rr, gr + rr));
      bs[i] = fminf(bs[i], fminf(sl + rr, sr + rr));
      m = fmaxf(m, fmaxf(bg[i], bs[i]));
    }
  }

  // fused loss: dsq=(out1-gt)^2; accumulate dsq*dt2 per mask and max(dt2)
  float mg = 0.f, ms = 0.f, sgf = 0.f, ssf = 0.f;
#pragma unroll
  for (int i = 0; i < 8; ++i) {
    float dq = (oV[i] - tV[i]) * (oV[i] - tV[i]);
    sgf += dq * bg[i];
    ssf += dq * bs[i];
    mg = fmaxf(mg, bg[i]);
    ms = fmaxf(ms, bs[i]);
  }
  double sgd = (double)sgf, ssd = (double)ssf;
#pragma unroll
  for (int off = 32; off; off >>= 1) {
    sgd += __shfl_down(sgd, off);
    ssd += __shfl_down(ssd, off);
    mg = fmaxf(mg, __shfl_down(mg, off));
    ms = fmaxf(ms, __shfl_down(ms, off));
  }
  __shared__ double bsg[8], bss[8];
  __shared__ float bmg[8], bms[8];
  __shared__ unsigned int lastFlag;
  if (lane == 0) {
    bsg[wave] = sgd;
    bss[wave] = ssd;
    bmg[wave] = mg;
    bms[wave] = ms;
  }
  __syncthreads();
  if (tid == 0) {
    double tg = 0.0, ts = 0.0;
    float xg = 0.f, xs = 0.f;
#pragma unroll
    for (int wv = 0; wv < 8; ++wv) {
      tg += bsg[wv];
      ts += bss[wv];
      xg = fmaxf(xg, bmg[wv]);
      xs = fmaxf(xs, bms[wv]);
    }
    atomicAdd(&sums[b], tg);
    atomicAdd(&sums[8 + b], ts);
    atomicMax(&maxbuf[b], __float_as_uint(xg)); // vals >= 0: uint order ok
    atomicMax(&maxbuf[8 + b], __float_as_uint(xs));
    __threadfence(); // release our partials before announcing
    unsigned int old = atomicAdd(counter, 1u);
    lastFlag = (old == (unsigned int)(B * H / 8 - 1)) ? 1u : 0u;
  }
  __syncthreads();

  if (lastFlag && tid < 64) {
    __threadfence(); // acquire
    double t = 0.0;
    if (tid < 8) {
      // non-destructive atomic RMW read-back: coherent across XCDs
      double sgv = atomicAdd(&sums[tid], 0.0);
      double ssv = atomicAdd(&sums[8 + tid], 0.0);
      float xg = __uint_as_float(atomicMax(&maxbuf[tid], 0u));
      float xs = __uint_as_float(atomicMax(&maxbuf[8 + tid], 0u));
      t = sgv / (double)(xg > 0.f ? xg : 1.f) +
          ssv / (double)(xs > 0.f ? xs : 1.f);
    }
    t += __shfl_down(t, 4);
    t += __shfl_down(t, 2);
    t += __shfl_down(t, 1);
    if (tid == 0) out[0] = (float)(t * (1.0 / (double)BHW));
  }
}

extern "C" void kernel_launch(void* const* d_in, const int* in_sizes, int n_in,
                              void* d_out, int out_size, void* d_ws,
                              size_t ws_size, hipStream_t stream) {
  const float* output = (const float*)d_in[0]; // [8,2,512,512] f32
  const int* target = (const int*)d_in[1];     // [8,1,512,512] i32

  double* sums = (double*)d_ws;
  unsigned int* maxbuf = (unsigned int*)((char*)d_ws + 128);
  unsigned int* counter = (unsigned int*)((char*)d_ws + 192);
  unsigned int* hdr = (unsigned int*)d_ws;
  unsigned short* ud_gt = (unsigned short*)((char*)d_ws + 256);
  unsigned short* ud_seg = ud_gt + BHW;

  vert_kernel<<<dim3(256), 512, 0, stream>>>(output, target, ud_gt, ud_seg,
                                             hdr);
  horiz_kernel<<<dim3(B * H / 8), 512, 0, stream>>>(
      output, target, ud_gt, ud_seg, sums, maxbuf, counter, (float*)d_out);
}